// Round 1
// 140.903 us; speedup vs baseline: 1.0007x; 1.0007x over previous
//
#include <hip/hip_runtime.h>
#include <math.h>

// ---------------------------------------------------------------------------
// Single fused kernel, v2. Changes vs v1 (theory: store pipe starved by
// serialized redundant phase-1 + over-general phase-2):
//
//   * Zero tiles (entirely above the diagonal, ~45% of blocks) now skip
//     phase 1 entirely and start streaming zero stores at t=0. This both
//     removes ~half the redundant f64/bpermute work chip-wide and fills the
//     store pipe while compute blocks are still in their moments phase.
//   * Phase 2 is specialized: tiles fully below the diagonal drop the causal
//     integer compare (only ~1 tile per 16-row stripe actually crosses the
//     diagonal and takes the general path). Branches are block-uniform.
//   * Phase 1 arithmetic is UNCHANGED and order-identical -> bit-identical
//     threshold -> absmax unchanged.
//
//   Phase 1 — redundantly recomputes the batch's joint point moments in f64
//   (input is 32 KB/batch, L2-broadcast). Closed-form mean/std(ddof=1) of
//   the S*S pairwise dist_sq values:
//     sum_d  = 2N(S2x+S2y) - 2(S1x^2 + S1y^2)
//     sum_d2 = [2N S4x - 8 S3x S1x + 6 S2x^2] + [same for y]
//            + 2*[2N A22 - 4 A21 S1y - 4 A12 S1x + 2 S2x S2y + 4 A11^2]
//   Reduction order is identical in every block -> bit-identical threshold.
//
//   forward_bias via 0.5 + 0.5*dx*rsqrt(d2) == 0.5*(1+cos(atan2(dy,dx)));
//   exactly 1.0 at the zero pair, matching atan2(0,1)=0.
// ---------------------------------------------------------------------------
#define PAB_ROWS 16
#define PAB_TPB  256   // threads per block; tile width = PAB_TPB*4 columns

template<bool CAUSAL>
__device__ __forceinline__ void pab_emit_rows(
        const float2* __restrict__ pis, const float* __restrict__ xs,
        const float* __restrict__ ys, float thr, int i0, int j0, int S,
        size_t orow, float* __restrict__ out) {
#pragma unroll
    for (int rr = 0; rr < PAB_ROWS; ++rr) {
        const int i = i0 + rr;
        if (i < S) {
            const float2 pi = pis[rr];
            float4 res;
            float* rp = &res.x;
#pragma unroll
            for (int k = 0; k < 4; ++k) {
                float dx = pi.x - xs[k];
                float dy = pi.y - ys[k];
                float d2 = fmaf(dx, dx, dy * dy);
                float bias = (d2 > 0.0f) ? fmaf(0.5f * dx, rsqrtf(d2), 0.5f)
                                         : 1.0f;
                bool valid = (d2 <= thr);
                if (CAUSAL) valid = valid && ((j0 + k) <= i);
                rp[k] = valid ? bias : 0.0f;
            }
            *(float4*)(out + orow) = res;
        }
        orow += S;
    }
}

__global__ __launch_bounds__(PAB_TPB) void pab_fused_kernel(
        const float* __restrict__ r, float* __restrict__ out, int S) {
    const int b = blockIdx.z;
    const float2* emb = (const float2*)r + (size_t)b * S;
    const int tid = threadIdx.x;

    const int i0  = blockIdx.y * PAB_ROWS;
    const int jt0 = blockIdx.x * PAB_TPB * 4;   // tile's first column
    const int j0  = jt0 + tid * 4;
    size_t orow = ((size_t)b * S + i0) * S + j0;

    // ---- Path A: tile entirely above the diagonal -> zeros only. --------
    // Block-uniform branch BEFORE phase 1 (no barriers crossed): these
    // blocks need no threshold and start saturating the store pipe
    // immediately. Harness poisons d_out, so zeros MUST be written.
    if (jt0 > i0 + PAB_ROWS - 1) {
        if (j0 < S) {
            const float4 z = {0.0f, 0.0f, 0.0f, 0.0f};
#pragma unroll
            for (int rr = 0; rr < PAB_ROWS; ++rr) {
                if (i0 + rr < S) *(float4*)(out + orow) = z;
                orow += S;
            }
        }
        return;
    }

    // ---------------- Phase 1: batch moments (nonzero tiles only) --------
    double s[12];
#pragma unroll
    for (int k = 0; k < 12; ++k) s[k] = 0.0;

    for (int idx0 = tid * 4; idx0 < S; idx0 += PAB_TPB * 4) {
        float4 c0 = *(const float4*)(emb + idx0);      // p0, p1
        float4 c1 = *(const float4*)(emb + idx0 + 2);  // p2, p3
        float xs[4] = {c0.x, c0.z, c1.x, c1.z};
        float ys[4] = {c0.y, c0.w, c1.y, c1.w};
#pragma unroll
        for (int k = 0; k < 4; ++k) {
            if (idx0 + k >= S) break;
            double x = (double)xs[k], y = (double)ys[k];
            double x2 = x * x, y2 = y * y;
            s[0]  += x;        s[1]  += y;
            s[2]  += x2;       s[3]  += y2;
            s[4]  += x2 * x;   s[5]  += y2 * y;
            s[6]  += x2 * x2;  s[7]  += y2 * y2;
            s[8]  += x * y;    s[9]  += x2 * y;
            s[10] += x * y2;   s[11] += x2 * y2;
        }
    }

    // Wave (64-lane) shuffle reduction — no barriers.
#pragma unroll
    for (int off = 32; off > 0; off >>= 1) {
#pragma unroll
        for (int k = 0; k < 12; ++k)
            s[k] += __shfl_down(s[k], off, 64);
    }

    __shared__ double part[PAB_TPB / 64][12];
    __shared__ double tot[12];
    __shared__ float thr_sh;
    const int wave = tid >> 6, lane = tid & 63;
    if (lane == 0) {
#pragma unroll
        for (int k = 0; k < 12; ++k) part[wave][k] = s[k];
    }
    __syncthreads();
    if (tid < 12) {
        double t = 0.0;
#pragma unroll
        for (int w = 0; w < PAB_TPB / 64; ++w) t += part[w][tid];
        tot[tid] = t;
    }
    __syncthreads();
    if (tid == 0) {
        double N = (double)S;
        double M = N * N;
        double S1x = tot[0], S1y = tot[1], S2x = tot[2], S2y = tot[3];
        double S3x = tot[4], S3y = tot[5], S4x = tot[6], S4y = tot[7];
        double A11 = tot[8], A21 = tot[9], A12 = tot[10], A22 = tot[11];

        double sum_d = 2.0 * N * (S2x + S2y) - 2.0 * (S1x * S1x + S1y * S1y);
        double qx = 2.0 * N * S4x - 8.0 * S3x * S1x + 6.0 * S2x * S2x;
        double qy = 2.0 * N * S4y - 8.0 * S3y * S1y + 6.0 * S2y * S2y;
        double cross = 2.0 * N * A22 - 4.0 * A21 * S1y - 4.0 * A12 * S1x
                     + 2.0 * S2x * S2y + 4.0 * A11 * A11;
        double sum_d2 = qx + qy + 2.0 * cross;

        double mean = sum_d / M;
        double var  = (sum_d2 - sum_d * sum_d / M) / (M - 1.0);  // ddof=1
        thr_sh = (float)(mean + 1.25 * sqrt(var));
    }
    __syncthreads();
    const float thr = thr_sh;

    // ---------------- Phase 2: write the 16 x 1024 tile ------------------
    if (j0 >= S) return;   // after all barriers — safe

    // Hoist the 16 block-uniform row points (scalar loads, issued together).
    float2 pis[PAB_ROWS];
#pragma unroll
    for (int rr = 0; rr < PAB_ROWS; ++rr)
        pis[rr] = emb[min(i0 + rr, S - 1)];

    float4 c0 = *(const float4*)(emb + j0);
    float4 c1 = *(const float4*)(emb + j0 + 2);
    const float xs[4] = {c0.x, c0.z, c1.x, c1.z};
    const float ys[4] = {c0.y, c0.w, c1.y, c1.w};

    // Block-uniform specialization: tile fully below the diagonal needs no
    // causal compare (worst row is i0: need jt0 + TILE_W - 1 <= i0).
    if (jt0 + PAB_TPB * 4 - 1 <= i0) {
        pab_emit_rows<false>(pis, xs, ys, thr, i0, j0, S, orow, out);
    } else {
        pab_emit_rows<true>(pis, xs, ys, thr, i0, j0, S, orow, out);
    }
}

extern "C" void kernel_launch(void* const* d_in, const int* in_sizes, int n_in,
                              void* d_out, int out_size, void* d_ws, size_t ws_size,
                              hipStream_t stream) {
    const float* r = (const float*)d_in[0];
    float* out = (float*)d_out;
    (void)d_ws; (void)ws_size;

    // in_sizes[0] = B*S*2, out_size = B*S*S  ->  S = 2*out_size / in_sizes[0]
    long in0 = in_sizes[0];
    int S = (int)((2L * (long)out_size) / in0);
    int B = (int)(in0 / (2L * S));

    dim3 block(PAB_TPB);
    dim3 grid((S + PAB_TPB * 4 - 1) / (PAB_TPB * 4),
              (S + PAB_ROWS - 1) / PAB_ROWS, B);
    pab_fused_kernel<<<grid, block, 0, stream>>>(r, out, S);
}